// Round 5
// baseline (967.486 us; speedup 1.0000x reference)
//
#include <hip/hip_runtime.h>
#include <hip/hip_bf16.h>
#include <math.h>

#define NN 50000
#define DD 128
#define RR 16
#define NBASIS 10
#define NE 1600000
#define NSEG (NN * RR)                  // 800000 segments (dst,rel)
#define NPART ((NSEG + 1023) / 1024)    // 782
#define KTOT 2304                       // (16 rel + time + x) * 128
#define DECAY 0.1f

typedef short bf16x8 __attribute__((ext_vector_type(8)));
typedef float f32x4 __attribute__((ext_vector_type(4)));

__device__ __forceinline__ ushort f2b(float f) {
    unsigned u = __float_as_uint(f);
    unsigned r = (u + 0x7FFFu + ((u >> 16) & 1u)) >> 16;
    return (ushort)r;
}
__device__ __forceinline__ float b2f(ushort u) {
    return __uint_as_float(((unsigned)u) << 16);
}

// ---------------- reduction slots ----------------
__global__ void k_init(unsigned* red) {
    if (threadIdx.x == 0) {
        red[0] = 0u;              // max(t) bits (t>=0: uint order == float order)
        red[1] = 0x7F800000u;     // min(t) = +inf
        ((float*)red)[2] = 0.0f;  // sum of unnormalized w
    }
}

__global__ void k_minmax(const float* __restrict__ t, unsigned* red) {
    float mx = 0.0f, mn = 1e30f;
    int stride = gridDim.x * blockDim.x;
    for (int i = blockIdx.x * blockDim.x + threadIdx.x; i < NE; i += stride) {
        float v = t[i];
        mx = fmaxf(mx, v);
        mn = fminf(mn, v);
    }
    for (int o = 32; o >= 1; o >>= 1) {
        mx = fmaxf(mx, __shfl_down(mx, o, 64));
        mn = fminf(mn, __shfl_down(mn, o, 64));
    }
    if ((threadIdx.x & 63) == 0) {
        atomicMax(&red[0], __float_as_uint(mx));
        atomicMin(&red[1], __float_as_uint(mn));
    }
}

__global__ void k_sumw(const float* __restrict__ t, unsigned* red) {
    float tmax = __uint_as_float(red[0]);
    float tmin = __uint_as_float(red[1]);
    float rtd  = 1.0f / (tmax - tmin + 1e-8f);
    float s = 0.0f;
    int stride = gridDim.x * blockDim.x;
    for (int i = blockIdx.x * blockDim.x + threadIdx.x; i < NE; i += stride)
        s += expf(-DECAY * (tmax - t[i]) * rtd);
    for (int o = 32; o >= 1; o >>= 1) s += __shfl_down(s, o, 64);
    if ((threadIdx.x & 63) == 0) atomicAdd(((float*)red) + 2, s);
}

// ---------------- segment histogram ----------------
__global__ void k_cnt(const int* __restrict__ edst, const int* __restrict__ etype,
                      unsigned* __restrict__ cnt) {
    int e = blockIdx.x * 256 + threadIdx.x;
    if (e >= NE) return;
    atomicAdd(&cnt[edst[e] * RR + etype[e]], 1u);
}

// ---------------- hierarchical exclusive scan over cnt[NSEG] ----------------
__global__ __launch_bounds__(1024) void k_scan1(const unsigned* __restrict__ cnt,
                                                unsigned* __restrict__ segptr,
                                                unsigned* __restrict__ part) {
    __shared__ unsigned sh[1024];
    int tid = threadIdx.x;
    int i = blockIdx.x * 1024 + tid;
    unsigned v = (i < NSEG) ? cnt[i] : 0u;
    sh[tid] = v;
    __syncthreads();
    for (int off = 1; off < 1024; off <<= 1) {
        unsigned t = (tid >= off) ? sh[tid - off] : 0u;
        __syncthreads();
        sh[tid] += t;
        __syncthreads();
    }
    if (i < NSEG) segptr[i] = sh[tid] - v;       // exclusive, block-local
    if (tid == 1023) part[blockIdx.x] = sh[1023];
}

__global__ __launch_bounds__(1024) void k_scan2(unsigned* __restrict__ part) {
    __shared__ unsigned sh[1024];
    int tid = threadIdx.x;
    unsigned v = (tid < NPART) ? part[tid] : 0u;
    sh[tid] = v;
    __syncthreads();
    for (int off = 1; off < 1024; off <<= 1) {
        unsigned t = (tid >= off) ? sh[tid - off] : 0u;
        __syncthreads();
        sh[tid] += t;
        __syncthreads();
    }
    if (tid < NPART) part[tid] = sh[tid] - v;    // exclusive
}

__global__ __launch_bounds__(1024) void k_scan3(unsigned* __restrict__ segptr,
                                                const unsigned* __restrict__ part) {
    int i = blockIdx.x * 1024 + threadIdx.x;
    if (i < NSEG) segptr[i] += part[i >> 10];
}

// ---------------- reorder edges into segment-sorted packed records ----------------
// record = src (low 16) | bf16(w) (high 16). After this kernel segptr[s] = END of seg s.
__global__ void k_reorder(const int* __restrict__ esrc, const int* __restrict__ edst,
                          const int* __restrict__ etype, const float* __restrict__ etime,
                          const unsigned* __restrict__ red,
                          unsigned* __restrict__ segptr,
                          unsigned* __restrict__ srcw) {
    int e = blockIdx.x * 256 + threadIdx.x;
    if (e >= NE) return;
    int seg = edst[e] * RR + etype[e];
    unsigned pos = atomicAdd(&segptr[seg], 1u);
    float tmax = __uint_as_float(red[0]);
    float tmin = __uint_as_float(red[1]);
    float w = expf(-DECAY * (tmax - etime[e]) / (tmax - tmin + 1e-8f));
    srcw[pos] = (unsigned)(esrc[e] & 0xFFFF) | ((unsigned)f2b(w) << 16);
}

// ---------------- x -> bf16 ----------------
__global__ void k_xb(const float* __restrict__ x, ushort* __restrict__ xb) {
    int i = blockIdx.x * 256 + threadIdx.x;
    if (i >= NN * (DD / 4)) return;
    float4 v = ((const float4*)x)[i];
    ushort4 o;
    o.x = f2b(v.x); o.y = f2b(v.y); o.z = f2b(v.z); o.w = f2b(v.w);
    ((ushort4*)xb)[i] = o;
}

// ---------------- Bt3[j][k] bf16, k = r*128 + d ----------------
// r<16: W_r[d][j]=sum_b comp[r,b]*basis[b,d,j];  r=16: tp_w[d][j];  r=17: root[d][j]
__global__ void k_bt3(const float* __restrict__ basis, const float* __restrict__ comp,
                      const float* __restrict__ root,  const float* __restrict__ tp_w,
                      ushort* __restrict__ Bt3) {
    int idx = blockIdx.x * 256 + threadIdx.x;
    if (idx >= DD * KTOT) return;
    int j = idx / KTOT, k = idx - j * KTOT;
    int r = k >> 7, d = k & 127;
    float v;
    if (r < RR) {
        v = 0.0f;
        for (int b = 0; b < NBASIS; ++b)
            v = fmaf(comp[r * NBASIS + b], basis[(b * DD + d) * DD + j], v);
    } else if (r == RR) {
        v = tp_w[d * DD + j];
    } else {
        v = root[d * DD + j];
    }
    Bt3[idx] = f2b(v);
}

// ---------------- fused gather + MFMA GEMM + bias/relu/layernorm ----------------
// Block: 256 thr (4 waves), 16 dst nodes. Two K-passes of 9 k-blocks each:
//   pass0: rel 0..8; pass1: rel 9..15 + xt (kb16) + x (kb17).
// Wave w gathers local rows w*4..w*4+3 into swizzled LDS A-tile, then computes
// col-tiles ct = {2w, 2w+1} with bF streamed from L2. C carried in regs; LN fused.
__global__ __launch_bounds__(256) void k_fused(
    const ushort* __restrict__ xb, const unsigned* __restrict__ srcw,
    const unsigned* __restrict__ segptr, const unsigned* __restrict__ red,
    const ushort* __restrict__ Bt3,
    const float* __restrict__ bias, const float* __restrict__ tpb,
    const float* __restrict__ gamma, const float* __restrict__ beta,
    float* __restrict__ out)
{
    __shared__ unsigned Als[9 * 16 * 64];   // 36 KB: [kbL][row][swizzled 64 dw]
    __shared__ float lnred[2][4][16];       // s,q partials [wave][row]

    const int tid  = threadIdx.x;
    const int w    = tid >> 6, lane = tid & 63;
    const int quad = lane >> 4, l16 = lane & 15;
    const int n0   = blockIdx.x * 16;
    const float sumw = ((const float*)red)[2];

    float xt0[4] = {0, 0, 0, 0}, xt1[4] = {0, 0, 0, 0};
    unsigned degacc[4] = {0, 0, 0, 0};
    unsigned startv[4];
    f32x4 acc0 = {0, 0, 0, 0}, acc1 = {0, 0, 0, 0};

#pragma unroll
    for (int i = 0; i < 4; ++i) {
        int n = n0 + w * 4 + i;
        startv[i] = (n == 0) ? 0u : ((n < NN) ? segptr[(unsigned)n * RR - 1u] : 0u);
    }

    for (int pass = 0; pass < 2; ++pass) {
        const int kbBase = pass ? 9 : 0;
        const int nrel   = pass ? 7 : 9;
        // ---- gather phase ----
        for (int i = 0; i < 4; ++i) {
            const int lr = w * 4 + i;
            const int n  = n0 + lr;
            const bool valid = (n < NN);
            unsigned start = startv[i];
            const unsigned s0 = (unsigned)n * RR;
            const int wslot = ((lane >> 2) ^ lr) * 4 + (lane & 3);   // swizzled dword
            for (int rr_ = 0; rr_ < nrel; ++rr_) {
                const int r = kbBase + rr_;
                unsigned c = 0;
                if (valid) c = segptr[s0 + r] - start;
                float a0 = 0.0f, a1 = 0.0f;
                for (unsigned e = start; e < start + c; ++e) {
                    unsigned rec = srcw[e];
                    float wgt = b2f((ushort)(rec >> 16));
                    unsigned pv = ((const unsigned*)(xb + (size_t)(rec & 0xFFFFu) * DD))[lane];
                    float vx = b2f((ushort)(pv & 0xFFFFu));
                    float vy = b2f((ushort)(pv >> 16));
                    a0 += vx; a1 += vy;
                    xt0[i] = fmaf(wgt, vx, xt0[i]);
                    xt1[i] = fmaf(wgt, vy, xt1[i]);
                }
                start += c; degacc[i] += c;
                float scl = c ? (1.0f / (float)c) : 0.0f;
                Als[rr_ * 1024 + lr * 64 + wslot] =
                    (unsigned)f2b(a0 * scl) | ((unsigned)f2b(a1 * scl) << 16);
            }
            startv[i] = start;
            if (pass == 1) {
                float s2 = 1.0f / ((sumw + 1e-8f) * fmaxf((float)degacc[i], 1.0f));
                Als[7 * 1024 + lr * 64 + wslot] =
                    (unsigned)f2b(xt0[i] * s2) | ((unsigned)f2b(xt1[i] * s2) << 16);
                unsigned xv = valid ? ((const unsigned*)(xb + (size_t)n * DD))[lane] : 0u;
                Als[8 * 1024 + lr * 64 + wslot] = xv;
            }
        }
        __syncthreads();
        // ---- GEMM phase: kbs [kbBase, kbBase+9) ----
        const int col0 = w * 32 + l16;
        const ushort* b0base = Bt3 + (size_t)col0 * KTOT + quad * 8;
        const ushort* b1base = b0base + (size_t)16 * KTOT;
#pragma unroll
        for (int kbL = 0; kbL < 9; ++kbL) {
            const int kb = kbBase + kbL;
#pragma unroll
            for (int ks = 0; ks < 4; ++ks) {
                const int g = ks * 4 + quad;
                bf16x8 aF  = *(const bf16x8*)&Als[kbL * 1024 + l16 * 64 + ((g ^ l16) << 2)];
                bf16x8 bF0 = *(const bf16x8*)(b0base + kb * 128 + ks * 32);
                bf16x8 bF1 = *(const bf16x8*)(b1base + kb * 128 + ks * 32);
                acc0 = __builtin_amdgcn_mfma_f32_16x16x32_bf16(aF, bF0, acc0, 0, 0, 0);
                acc1 = __builtin_amdgcn_mfma_f32_16x16x32_bf16(aF, bF1, acc1, 0, 0, 0);
            }
        }
        __syncthreads();
    }

    // ---- epilogue: bias + relu + LN (cross-wave via LDS) ----
    const int c0 = w * 32 + l16, c1 = c0 + 16;
    const float bc0 = bias[c0] + tpb[c0], bc1 = bias[c1] + tpb[c1];
    const float g0 = gamma[c0], g1 = gamma[c1];
    const float be0 = beta[c0], be1 = beta[c1];

    float s[4], q[4];
#pragma unroll
    for (int reg = 0; reg < 4; ++reg) {
        float v0 = fmaxf(acc0[reg] + bc0, 0.0f);
        float v1 = fmaxf(acc1[reg] + bc1, 0.0f);
        acc0[reg] = v0; acc1[reg] = v1;
        s[reg] = v0 + v1;
        q[reg] = v0 * v0 + v1 * v1;
    }
#pragma unroll
    for (int off = 1; off < 16; off <<= 1)
#pragma unroll
        for (int reg = 0; reg < 4; ++reg) {
            s[reg] += __shfl_xor(s[reg], off, 64);
            q[reg] += __shfl_xor(q[reg], off, 64);
        }
    if (l16 == 0) {
#pragma unroll
        for (int reg = 0; reg < 4; ++reg) {
            lnred[0][w][quad * 4 + reg] = s[reg];
            lnred[1][w][quad * 4 + reg] = q[reg];
        }
    }
    __syncthreads();
#pragma unroll
    for (int reg = 0; reg < 4; ++reg) {
        const int row = quad * 4 + reg;
        float S = lnred[0][0][row] + lnred[0][1][row] + lnred[0][2][row] + lnred[0][3][row];
        float Q = lnred[1][0][row] + lnred[1][1][row] + lnred[1][2][row] + lnred[1][3][row];
        float mu  = S * (1.0f / DD);
        float var = Q * (1.0f / DD) - mu * mu;
        float inv = rsqrtf(var + 1e-5f);
        const int n = n0 + row;
        if (n < NN) {
            out[(size_t)n * DD + c0] = (acc0[reg] - mu) * inv * g0 + be0;
            out[(size_t)n * DD + c1] = (acc1[reg] - mu) * inv * g1 + be1;
        }
    }
}

extern "C" void kernel_launch(void* const* d_in, const int* in_sizes, int n_in,
                              void* d_out, int out_size, void* d_ws, size_t ws_size,
                              hipStream_t stream)
{
    const float* x     = (const float*)d_in[0];
    const int*   ei    = (const int*)d_in[1];
    const int*   etype = (const int*)d_in[2];
    const float* etime = (const float*)d_in[3];
    const float* basis = (const float*)d_in[4];
    const float* comp  = (const float*)d_in[5];
    const float* root  = (const float*)d_in[6];
    const float* bias  = (const float*)d_in[7];
    const float* tp_w  = (const float*)d_in[8];
    const float* tp_b  = (const float*)d_in[9];
    const float* gamma = (const float*)d_in[10];
    const float* beta  = (const float*)d_in[11];
    float* out = (float*)d_out;

    char* ws = (char*)d_ws;
    size_t off = 0;
    auto alloc = [&](size_t bytes) -> void* {
        void* p = ws + off;
        off = (off + bytes + 255) & ~(size_t)255;
        return p;
    };
    unsigned* red    = (unsigned*)alloc(64);
    unsigned* cnt    = (unsigned*)alloc((size_t)NSEG * 4);      //  3.2 MB
    unsigned* segptr = (unsigned*)alloc((size_t)NSEG * 4);      //  3.2 MB
    unsigned* part   = (unsigned*)alloc(1024 * 4);              //  4 KB
    unsigned* srcw   = (unsigned*)alloc((size_t)NE * 4);        //  6.4 MB
    ushort*   xb     = (ushort*)alloc((size_t)NN * DD * 2);     // 12.8 MB
    ushort*   Bt3    = (ushort*)alloc((size_t)DD * KTOT * 2);   //  0.59 MB
    (void)ws_size;

    const int* esrc = ei;
    const int* edst = ei + NE;

    hipLaunchKernelGGL(k_init, dim3(1), dim3(64), 0, stream, red);
    hipLaunchKernelGGL(k_minmax, dim3(1024), dim3(256), 0, stream, etime, red);
    hipLaunchKernelGGL(k_sumw, dim3(1024), dim3(256), 0, stream, etime, red);

    hipMemsetAsync(cnt, 0, (size_t)NSEG * 4, stream);
    hipLaunchKernelGGL(k_cnt, dim3((NE + 255) / 256), dim3(256), 0, stream,
                       edst, etype, cnt);

    hipLaunchKernelGGL(k_scan1, dim3(NPART), dim3(1024), 0, stream, cnt, segptr, part);
    hipLaunchKernelGGL(k_scan2, dim3(1), dim3(1024), 0, stream, part);
    hipLaunchKernelGGL(k_scan3, dim3(NPART), dim3(1024), 0, stream, segptr, part);

    hipLaunchKernelGGL(k_reorder, dim3((NE + 255) / 256), dim3(256), 0, stream,
                       esrc, edst, etype, etime, red, segptr, srcw);

    hipLaunchKernelGGL(k_xb, dim3((NN * (DD / 4) + 255) / 256), dim3(256), 0, stream, x, xb);
    hipLaunchKernelGGL(k_bt3, dim3((DD * KTOT + 255) / 256), dim3(256), 0, stream,
                       basis, comp, root, tp_w, Bt3);

    hipLaunchKernelGGL(k_fused, dim3((NN + 15) / 16), dim3(256), 0, stream,
                       xb, srcw, segptr, red, Bt3, bias, tp_b, gamma, beta, out);
}